// Round 7
// baseline (158.911 us; speedup 1.0000x reference)
//
#include <hip/hip_runtime.h>

typedef float  f32x4 __attribute__((ext_vector_type(4)));
typedef short  s16x8 __attribute__((ext_vector_type(8)));

#define REC_LDS_BYTES 73216   // 64K weights + 4K h + 1.5K bias + 2K paths

__device__ __forceinline__ unsigned short bfb(float x) {  // f32 -> bf16 bits, RNE
  unsigned u = __builtin_bit_cast(unsigned, x);
  return (unsigned short)((u + 0x7FFFu + ((u >> 16) & 1u)) >> 16);
}
__device__ __forceinline__ float fast_sig(float x) {
  float e = __builtin_amdgcn_exp2f(x * -1.44269504f);
  return __builtin_amdgcn_rcpf(1.f + e);
}
__device__ __forceinline__ float fast_tanh(float x) {
  float e = __builtin_amdgcn_exp2f(x * 2.88539008f);
  return 1.f - 2.f * __builtin_amdgcn_rcpf(1.f + e);
}

// ---------- Phase 1: vocab tables (blocks 0..300) + weight A-fragments (301..308)
//            + length counting-sort (block 309) ----------
// frags[((mat*8 + T)*4 + kk)*64 + lane], mat in {z,r,u}, T = 16-row tile 0..7.
// A-frag (mfma_f32_16x16x32_bf16): lane l holds A row = l&15, k = (l>>4)*8 + j
__global__ __launch_bounds__(256) void tab_kernel(
    const float* __restrict__ emb,
    const float* __restrict__ Wi, const float* __restrict__ bi,
    const float* __restrict__ Ww, const float* __restrict__ bw,
    const float* __restrict__ Wh, const float* __restrict__ Wu,
    const int* __restrict__ pmask, int* __restrict__ perm,
    float* __restrict__ xi_tab, float* __restrict__ xw_tab,
    s16x8* __restrict__ frags)
{
  if (blockIdx.x == 309) {   // counting-sort rows by length (ascending)
    __shared__ int hist[33];
    __shared__ int base2[33];
    const int tid = threadIdx.x;
    if (tid < 33) hist[tid] = 0;
    __syncthreads();
    for (int i = tid; i < 8192; i += 256) atomicAdd(&hist[pmask[i]], 1);
    __syncthreads();
    if (tid == 0) {
      int acc = 0;
      for (int l = 1; l <= 32; ++l) { base2[l] = acc; acc += hist[l]; }
    }
    __syncthreads();
    for (int i = tid; i < 8192; i += 256) {
      const int pos = atomicAdd(&base2[pmask[i]], 1);
      perm[pos] = i;
    }
    return;
  }
  if (blockIdx.x >= 301) {
    const int T = blockIdx.x - 301;      // tile 0..7
    const int lane = threadIdx.x;
    if (lane >= 64) return;
    const int a = lane & 15, s = lane >> 4;
    const float* rowp[3];
    rowp[0] = Wh + (16 * T + a) * 128;          // z tile
    rowp[1] = Wh + (128 + 16 * T + a) * 128;    // r tile
    rowp[2] = Wu + (16 * T + a) * 128;          // hu tile
    #pragma unroll
    for (int mat = 0; mat < 3; ++mat) {
      #pragma unroll
      for (int kk = 0; kk < 4; ++kk) {
        const float* src = rowp[mat] + 32 * kk + 8 * s;
        const float4 A = *(const float4*)src;
        const float4 B = *(const float4*)(src + 4);
        s16x8 v;
        v[0] = (short)bfb(A.x); v[1] = (short)bfb(A.y);
        v[2] = (short)bfb(A.z); v[3] = (short)bfb(A.w);
        v[4] = (short)bfb(B.x); v[5] = (short)bfb(B.y);
        v[6] = (short)bfb(B.z); v[7] = (short)bfb(B.w);
        frags[((mat * 8 + T) * 4 + kk) * 64 + lane] = v;
      }
    }
    return;
  }

  const int v = blockIdx.x;            // 0..300
  const int g = threadIdx.x;           // 0..255
  const float4* er = (const float4*)(emb + v * 128);

  float acc = bi[g];
  const float4* wr = (const float4*)(Wi + g * 128);
  #pragma unroll 8
  for (int j = 0; j < 32; ++j) {
    float4 e = er[j], w4 = wr[j];
    acc = fmaf(e.x, w4.x, acc); acc = fmaf(e.y, w4.y, acc);
    acc = fmaf(e.z, w4.z, acc); acc = fmaf(e.w, w4.w, acc);
  }
  float accw = 0.f;
  if (g < 128) {
    accw = bw[g];
    const float4* wr2 = (const float4*)(Ww + g * 128);
    #pragma unroll 8
    for (int j = 0; j < 32; ++j) {
      float4 e = er[j], w4 = wr2[j];
      accw = fmaf(e.x, w4.x, accw); accw = fmaf(e.y, w4.y, accw);
      accw = fmaf(e.z, w4.z, accw); accw = fmaf(e.w, w4.w, accw);
    }
  }
  __shared__ float rs[4][2], rw[2][2];
  float s = acc, q = acc * acc;
  #pragma unroll
  for (int m = 1; m < 64; m <<= 1) { s += __shfl_xor(s, m); q += __shfl_xor(q, m); }
  if ((threadIdx.x & 63) == 0) { rs[threadIdx.x >> 6][0] = s; rs[threadIdx.x >> 6][1] = q; }
  float sw_ = accw, qw_ = accw * accw;
  #pragma unroll
  for (int m = 1; m < 64; m <<= 1) { sw_ += __shfl_xor(sw_, m); qw_ += __shfl_xor(qw_, m); }
  if (g < 128 && (g & 63) == 0) { rw[g >> 6][0] = sw_; rw[g >> 6][1] = qw_; }
  __syncthreads();
  const float SH = rs[0][0] + rs[1][0] + rs[2][0] + rs[3][0];
  const float QH = rs[0][1] + rs[1][1] + rs[2][1] + rs[3][1];
  const float mH = SH * (1.f / 256.f);
  const float rH = rsqrtf(fmaxf(QH * (1.f / 256.f) - mH * mH, 0.f) + 1e-5f);
  xi_tab[v * 256 + g] = (acc - mH) * rH;
  if (g < 128) {
    const float SW = rw[0][0] + rw[1][0], QW = rw[0][1] + rw[1][1];
    const float mW = SW * (1.f / 128.f);
    const float rW = rsqrtf(fmaxf(QW * (1.f / 128.f) - mW * mW, 0.f) + 1e-5f);
    xw_tab[v * 128 + g] = (accw - mW) * rW;
  }
}

// ---------- Phase 2: recurrence. 512 blocks x 64 thr (ONE wave, 16 rows) ----------
// Wave owns ALL 24 gate tiles for its 16 rows -> zero __syncthreads in the loop.
// Wh (z,r) tiles stream from LDS; Wu tiles live in registers; biases = MFMA acc init.
// Thread (s=lane>>4, r=lane&15): outputs g = 16T + 4s + i (T=0..7), h-row r.
__global__ __launch_bounds__(64, 1) void rec_kernel(
    const int* __restrict__ paths, const int* __restrict__ pmask,
    const int* __restrict__ perm,
    const float* __restrict__ bh, const float* __restrict__ bu,
    const float* __restrict__ xi_tab, const float* __restrict__ xw_tab,
    const s16x8* __restrict__ frags,
    float* __restrict__ out)
{
  extern __shared__ char smem[];
  s16x8* wlds = (s16x8*)smem;                         // [2*8*4][64] = 64 KB (z,r frags)
  unsigned char* hbuf = (unsigned char*)(smem + 65536); // [16][128] bf16, XOR(r)-swizzled
  float* blds = (float*)(smem + 69632);               // [384] f32 biases (z|r|u)
  int* plT = (int*)(smem + 71168);                    // [32 t][16 r]

  const int lane = threadIdx.x;
  const int s    = lane >> 4;
  const int r    = lane & 15;
  // long+short pairing: CU c hosts blocks c and c+256 -> grps {c, 511-c}
  const int grp  = (blockIdx.x < 256) ? blockIdx.x : 767 - blockIdx.x;
  const int base = grp * 16;

  // ---- stage: Wh z,r frags -> LDS (64 KB, coalesced b128 copy) ----
  #pragma unroll 4
  for (int i = 0; i < 64; ++i)
    wlds[i * 64 + lane] = frags[i * 64 + lane];
  // Wu tiles -> registers (32 frags = 128 VGPR)
  s16x8 wu[8][4];
  #pragma unroll
  for (int T = 0; T < 8; ++T)
    #pragma unroll
    for (int kk = 0; kk < 4; ++kk)
      wu[T][kk] = frags[((16 + T) * 4 + kk) * 64 + lane];
  // biases -> LDS
  #pragma unroll
  for (int i = 0; i < 4; ++i) blds[lane + 64 * i] = bh[lane + 64 * i];
  #pragma unroll
  for (int i = 0; i < 2; ++i) blds[256 + lane + 64 * i] = bu[lane + 64 * i];
  // h = 0
  {
    uint4 z{0u, 0u, 0u, 0u};
    #pragma unroll
    for (int i = 0; i < 4; ++i) ((uint4*)hbuf)[i * 64 + lane] = z;
  }
  // paths transposed
  #pragma unroll
  for (int k0 = 0; k0 < 512; k0 += 64) {
    const int k = k0 + lane;
    plT[(k >> 4) * 16 + (k & 15)] = paths[perm[base + (k & 15)] * 32 + (k >> 4)];
  }

  const int ri  = perm[base + r];
  const int len = pmask[ri];
  const int len_max = __shfl(len, 15);   // ascending bucket -> lane 15 (r=15) max

  int hoff[4];
  #pragma unroll
  for (int kk = 0; kk < 4; ++kk)
    hoff[kk] = r * 256 + (((4 * kk + s) ^ r) << 4);
  int hwadr[8];
  #pragma unroll
  for (int T = 0; T < 8; ++T)
    hwadr[T] = r * 256 + (((2 * T + (s >> 1)) ^ r) << 4) + (s & 1) * 8;

  f32x4 hold[8];
  #pragma unroll
  for (int T = 0; T < 8; ++T) hold[T] = f32x4{0.f, 0.f, 0.f, 0.f};

  float* orow = out + (size_t)ri * 256 + 4 * s;

  // NOTE: no __syncthreads needed anywhere — single wave; lgkmcnt orders LDS.
  #pragma unroll 1
  for (int t = 0; t < len_max; ++t) {
    const int p = plT[t * 16 + r];

    // ---- h B-frags ----
    s16x8 hb[4];
    #pragma unroll
    for (int kk = 0; kk < 4; ++kk)
      hb[kk] = *(const s16x8*)(hbuf + hoff[kk]);

    // ---- acc init = bias (LDS broadcast reads), then 96 MFMAs ----
    f32x4 az[8], ar[8], au[8];
    #pragma unroll
    for (int T = 0; T < 8; ++T) {
      az[T] = *(const f32x4*)&blds[16 * T + 4 * s];
      ar[T] = *(const f32x4*)&blds[128 + 16 * T + 4 * s];
      au[T] = *(const f32x4*)&blds[256 + 16 * T + 4 * s];
    }
    #pragma unroll
    for (int kk = 0; kk < 4; ++kk)
      #pragma unroll
      for (int T = 0; T < 8; ++T)
        au[T] = __builtin_amdgcn_mfma_f32_16x16x32_bf16(wu[T][kk], hb[kk], au[T], 0, 0, 0);
    #pragma unroll
    for (int T = 0; T < 8; ++T)
      #pragma unroll
      for (int kk = 0; kk < 4; ++kk)
        az[T] = __builtin_amdgcn_mfma_f32_16x16x32_bf16(wlds[(T * 4 + kk) * 64 + lane], hb[kk], az[T], 0, 0, 0);
    #pragma unroll
    for (int T = 0; T < 8; ++T)
      #pragma unroll
      for (int kk = 0; kk < 4; ++kk)
        ar[T] = __builtin_amdgcn_mfma_f32_16x16x32_bf16(wlds[((8 + T) * 4 + kk) * 64 + lane], hb[kk], ar[T], 0, 0, 0);

    // ---- xi/xw gathers (issued here, consumed ~400cy later in pointwise) ----
    f32x4 xiz[8], xir[8], xwv[8];
    #pragma unroll
    for (int T = 0; T < 8; ++T) {
      xiz[T] = *(const f32x4*)(xi_tab + p * 256 + 16 * T + 4 * s);
      xir[T] = *(const f32x4*)(xi_tab + p * 256 + 128 + 16 * T + 4 * s);
      xwv[T] = *(const f32x4*)(xw_tab + p * 128 + 16 * T + 4 * s);
    }

    // ---- LN stats (intra-wave: 4 lanes per row -> xor 16, 32) ----
    float sH = 0.f, qH = 0.f, sU = 0.f, qU = 0.f;
    #pragma unroll
    for (int T = 0; T < 8; ++T) {
      #pragma unroll
      for (int i = 0; i < 4; ++i) {
        sH += az[T][i]; qH = fmaf(az[T][i], az[T][i], qH);
        sH += ar[T][i]; qH = fmaf(ar[T][i], ar[T][i], qH);
        sU += au[T][i]; qU = fmaf(au[T][i], au[T][i], qU);
      }
    }
    sH += __shfl_xor(sH, 16); qH += __shfl_xor(qH, 16);
    sU += __shfl_xor(sU, 16); qU += __shfl_xor(qU, 16);
    sH += __shfl_xor(sH, 32); qH += __shfl_xor(qH, 32);
    sU += __shfl_xor(sU, 32); qU += __shfl_xor(qU, 32);

    const float mH = sH * (1.f / 256.f);
    const float rsH = rsqrtf(fmaxf(qH * (1.f / 256.f) - mH * mH, 0.f) + 1e-5f);
    const float cH = -mH * rsH;
    const float mU = sU * (1.f / 128.f);
    const float rsU = rsqrtf(fmaxf(qU * (1.f / 128.f) - mU * mU, 0.f) + 1e-5f);
    const float cU = -mU * rsU;

    // ---- pointwise + h feedback (wave-private LDS writes) ----
    const bool emit = (t == len - 1);
    #pragma unroll
    for (int T = 0; T < 8; ++T) {
      f32x4 hn;
      #pragma unroll
      for (int i = 0; i < 4; ++i) {
        const float zg = fast_sig(xiz[T][i] + fmaf(az[T][i], rsH, cH));
        const float rg = fast_sig(xir[T][i] + fmaf(ar[T][i], rsH, cH));
        const float hu = fmaf(au[T][i], rsU, cU);
        const float hh = fast_tanh(fmaf(rg, hu, xwv[T][i]));
        hn[i] = fmaf(zg, hh - hold[T][i], hold[T][i]);
      }
      const unsigned lo  = (unsigned)bfb(hn[0]) | ((unsigned)bfb(hn[1]) << 16);
      const unsigned hi2 = (unsigned)bfb(hn[2]) | ((unsigned)bfb(hn[3]) << 16);
      *(uint2*)(hbuf + hwadr[T]) = uint2{lo, hi2};
      if (emit)
        *(float4*)(orow + 16 * T) = float4{hn[0], hn[1], hn[2], hn[3]};
      hold[T] = hn;
    }
  }
}

// ---------- Phase 3: pair rows, final LN (verified) ----------
__global__ __launch_bounds__(256) void out_kernel(
    const float* __restrict__ gamma, const float* __restrict__ beta,
    float* __restrict__ out)
{
  const int tid = threadIdx.x;
  const int lane = tid & 63;
  const int m = blockIdx.x * 4 + (tid >> 6);
  float* pa = out + (size_t)(2 * m) * 256;
  float* pb = pa + 256;
  const float oa0 = pa[lane], oa1 = pa[64 + lane];
  const float ob0 = pb[lane], ob1 = pb[64 + lane];
  float s = oa0 + oa1 + ob0 + ob1;
  float q = oa0 * oa0 + oa1 * oa1 + ob0 * ob0 + ob1 * ob1;
  #pragma unroll
  for (int msk = 1; msk < 64; msk <<= 1) { s += __shfl_xor(s, msk); q += __shfl_xor(q, msk); }
  const float mean = s * (1.f / 256.f);
  const float rstd = rsqrtf(fmaxf(q * (1.f / 256.f) - mean * mean, 0.f) + 1e-5f);
  const float g0 = gamma[lane], g1 = gamma[64 + lane], g2 = gamma[128 + lane], g3 = gamma[192 + lane];
  const float b0 = beta[lane],  b1 = beta[64 + lane],  b2 = beta[128 + lane],  b3 = beta[192 + lane];
  const float na0 = (oa0 - mean) * rstd, na1 = (oa1 - mean) * rstd;
  const float nb0 = (ob0 - mean) * rstd, nb1 = (ob1 - mean) * rstd;
  pa[lane]       = na0 * g0 + b0;
  pa[64 + lane]  = na1 * g1 + b1;
  pa[128 + lane] = nb0 * g2 + b2;
  pa[192 + lane] = nb1 * g3 + b3;
  pb[lane]       = nb0 * g0 + b0;
  pb[64 + lane]  = nb1 * g1 + b1;
  pb[128 + lane] = na0 * g2 + b2;
  pb[192 + lane] = na1 * g3 + b3;
}

extern "C" void kernel_launch(void* const* d_in, const int* in_sizes, int n_in,
                              void* d_out, int out_size, void* d_ws, size_t ws_size,
                              hipStream_t stream) {
  const int*   paths = (const int*)d_in[0];
  const int*   pmask = (const int*)d_in[1];
  const float* emb   = (const float*)d_in[2];
  const float* Wi    = (const float*)d_in[3];
  const float* bi    = (const float*)d_in[4];
  const float* Wh    = (const float*)d_in[5];
  const float* bh    = (const float*)d_in[6];
  const float* Ww    = (const float*)d_in[7];
  const float* bw    = (const float*)d_in[8];
  const float* Wu    = (const float*)d_in[9];
  const float* bu    = (const float*)d_in[10];
  const float* gamma = (const float*)d_in[11];
  const float* beta  = (const float*)d_in[12];
  float* out = (float*)d_out;

  float* xi_tab = (float*)d_ws;                          // [301][256] f32
  float* xw_tab = xi_tab + 301 * 256;                    // [301][128] f32
  s16x8* frags  = (s16x8*)((char*)d_ws + 462336);        // [3*8*4][64] s16x8 = 96 KB
  int*   perm   = (int*)((char*)d_ws + 560640);          // [8192]

  hipFuncSetAttribute((const void*)rec_kernel,
                      hipFuncAttributeMaxDynamicSharedMemorySize, REC_LDS_BYTES);

  hipLaunchKernelGGL(tab_kernel, dim3(310), dim3(256), 0, stream,
                     emb, Wi, bi, Ww, bw, Wh, Wu, pmask, perm, xi_tab, xw_tab, frags);
  hipLaunchKernelGGL(rec_kernel, dim3(512), dim3(64), REC_LDS_BYTES, stream,
                     paths, pmask, perm, bh, bu, xi_tab, xw_tab, frags, out);
  hipLaunchKernelGGL(out_kernel, dim3(1024), dim3(256), 0, stream, gamma, beta, out);
}

// Round 8
// 119.398 us; speedup vs baseline: 1.3309x; 1.3309x over previous
//
#include <hip/hip_runtime.h>

typedef float  f32x4 __attribute__((ext_vector_type(4)));
typedef short  s16x8 __attribute__((ext_vector_type(8)));

__device__ __forceinline__ unsigned short bfb(float x) {  // f32 -> bf16 bits, RNE
  unsigned u = __builtin_bit_cast(unsigned, x);
  return (unsigned short)((u + 0x7FFFu + ((u >> 16) & 1u)) >> 16);
}
__device__ __forceinline__ float fast_sig(float x) {
  float e = __builtin_amdgcn_exp2f(x * -1.44269504f);
  return __builtin_amdgcn_rcpf(1.f + e);
}
__device__ __forceinline__ float fast_tanh(float x) {
  float e = __builtin_amdgcn_exp2f(x * 2.88539008f);
  return 1.f - 2.f * __builtin_amdgcn_rcpf(1.f + e);
}

// ---------- Phase 1: vocab tables (0..300) + weight A-frags (301..308) + sort (309) ----------
__global__ __launch_bounds__(256) void tab_kernel(
    const float* __restrict__ emb,
    const float* __restrict__ Wi, const float* __restrict__ bi,
    const float* __restrict__ Ww, const float* __restrict__ bw,
    const float* __restrict__ Wh, const float* __restrict__ Wu,
    const int* __restrict__ pmask, int* __restrict__ perm,
    float* __restrict__ xi_tab, float* __restrict__ xw_tab,
    s16x8* __restrict__ frags)
{
  if (blockIdx.x == 309) {   // counting-sort rows by length (ascending)
    __shared__ int hist[33];
    __shared__ int base2[33];
    const int tid = threadIdx.x;
    if (tid < 33) hist[tid] = 0;
    __syncthreads();
    for (int i = tid; i < 8192; i += 256) atomicAdd(&hist[pmask[i]], 1);
    __syncthreads();
    if (tid == 0) {
      int acc = 0;
      for (int l = 1; l <= 32; ++l) { base2[l] = acc; acc += hist[l]; }
    }
    __syncthreads();
    for (int i = tid; i < 8192; i += 256) {
      const int pos = atomicAdd(&base2[pmask[i]], 1);
      perm[pos] = i;
    }
    return;
  }
  if (blockIdx.x >= 301) {
    const int T = blockIdx.x - 301;      // tile 0..7
    const int lane = threadIdx.x;
    if (lane >= 64) return;
    const int a = lane & 15, s = lane >> 4;
    const float* rowp[3];
    rowp[0] = Wh + (16 * T + a) * 128;          // z tile
    rowp[1] = Wh + (128 + 16 * T + a) * 128;    // r tile
    rowp[2] = Wu + (16 * T + a) * 128;          // hu tile
    #pragma unroll
    for (int mat = 0; mat < 3; ++mat) {
      #pragma unroll
      for (int kk = 0; kk < 4; ++kk) {
        const float* src = rowp[mat] + 32 * kk + 8 * s;
        const float4 A = *(const float4*)src;
        const float4 B = *(const float4*)(src + 4);
        s16x8 v;
        v[0] = (short)bfb(A.x); v[1] = (short)bfb(A.y);
        v[2] = (short)bfb(A.z); v[3] = (short)bfb(A.w);
        v[4] = (short)bfb(B.x); v[5] = (short)bfb(B.y);
        v[6] = (short)bfb(B.z); v[7] = (short)bfb(B.w);
        frags[((mat * 8 + T) * 4 + kk) * 64 + lane] = v;
      }
    }
    return;
  }

  const int v = blockIdx.x;            // 0..300
  const int g = threadIdx.x;           // 0..255
  const float4* er = (const float4*)(emb + v * 128);

  float acc = bi[g];
  const float4* wr = (const float4*)(Wi + g * 128);
  #pragma unroll 8
  for (int j = 0; j < 32; ++j) {
    float4 e = er[j], w4 = wr[j];
    acc = fmaf(e.x, w4.x, acc); acc = fmaf(e.y, w4.y, acc);
    acc = fmaf(e.z, w4.z, acc); acc = fmaf(e.w, w4.w, acc);
  }
  float accw = 0.f;
  if (g < 128) {
    accw = bw[g];
    const float4* wr2 = (const float4*)(Ww + g * 128);
    #pragma unroll 8
    for (int j = 0; j < 32; ++j) {
      float4 e = er[j], w4 = wr2[j];
      accw = fmaf(e.x, w4.x, accw); accw = fmaf(e.y, w4.y, accw);
      accw = fmaf(e.z, w4.z, accw); accw = fmaf(e.w, w4.w, accw);
    }
  }
  __shared__ float rs[4][2], rw[2][2];
  float s = acc, q = acc * acc;
  #pragma unroll
  for (int m = 1; m < 64; m <<= 1) { s += __shfl_xor(s, m); q += __shfl_xor(q, m); }
  if ((threadIdx.x & 63) == 0) { rs[threadIdx.x >> 6][0] = s; rs[threadIdx.x >> 6][1] = q; }
  float sw_ = accw, qw_ = accw * accw;
  #pragma unroll
  for (int m = 1; m < 64; m <<= 1) { sw_ += __shfl_xor(sw_, m); qw_ += __shfl_xor(qw_, m); }
  if (g < 128 && (g & 63) == 0) { rw[g >> 6][0] = sw_; rw[g >> 6][1] = qw_; }
  __syncthreads();
  const float SH = rs[0][0] + rs[1][0] + rs[2][0] + rs[3][0];
  const float QH = rs[0][1] + rs[1][1] + rs[2][1] + rs[3][1];
  const float mH = SH * (1.f / 256.f);
  const float rH = rsqrtf(fmaxf(QH * (1.f / 256.f) - mH * mH, 0.f) + 1e-5f);
  xi_tab[v * 256 + g] = (acc - mH) * rH;
  if (g < 128) {
    const float SW = rw[0][0] + rw[1][0], QW = rw[0][1] + rw[1][1];
    const float mW = SW * (1.f / 128.f);
    const float rW = rsqrtf(fmaxf(QW * (1.f / 128.f) - mW * mW, 0.f) + 1e-5f);
    xw_tab[v * 128 + g] = (accw - mW) * rW;
  }
}

// ---------- Phase 2: recurrence. 256 blocks x 256 thr (4 waves), TWO 16-row groups ----------
// Pipeline: each barrier phase = {group Y: MFMA + stats-write} ∥ {group X: stats-read,
// LN, pointwise, h-write, table-prefetch}. 32 row-steps per barrier-pair.
__device__ __forceinline__ void mfma_stats(
    const unsigned char* hbufg, float* redg /* &red[g][w][0][0] */,
    const int (&hoff)[4],
    const s16x8 (&wz)[2][4], const s16x8 (&wr2)[2][4], const s16x8 (&wu2)[2][4],
    const f32x4 (&bz)[2], const f32x4 (&br2)[2], const f32x4 (&bu2)[2],
    int lane, int r,
    f32x4 (&az)[2], f32x4 (&ar)[2], f32x4 (&au)[2])
{
  s16x8 hb[4];
  #pragma unroll
  for (int kk = 0; kk < 4; ++kk) hb[kk] = *(const s16x8*)(hbufg + hoff[kk]);
  #pragma unroll
  for (int u = 0; u < 2; ++u) {
    az[u] = f32x4{0.f, 0.f, 0.f, 0.f}; ar[u] = az[u]; au[u] = az[u];
  }
  #pragma unroll
  for (int kk = 0; kk < 4; ++kk) {
    #pragma unroll
    for (int u = 0; u < 2; ++u) {
      az[u] = __builtin_amdgcn_mfma_f32_16x16x32_bf16(wz[u][kk],  hb[kk], az[u], 0, 0, 0);
      ar[u] = __builtin_amdgcn_mfma_f32_16x16x32_bf16(wr2[u][kk], hb[kk], ar[u], 0, 0, 0);
      au[u] = __builtin_amdgcn_mfma_f32_16x16x32_bf16(wu2[u][kk], hb[kk], au[u], 0, 0, 0);
    }
  }
  float sH = 0.f, qH = 0.f, sU = 0.f, qU = 0.f;
  #pragma unroll
  for (int u = 0; u < 2; ++u) {
    #pragma unroll
    for (int i = 0; i < 4; ++i) {
      az[u][i] += bz[u][i];  sH += az[u][i]; qH = fmaf(az[u][i], az[u][i], qH);
      ar[u][i] += br2[u][i]; sH += ar[u][i]; qH = fmaf(ar[u][i], ar[u][i], qH);
      au[u][i] += bu2[u][i]; sU += au[u][i]; qU = fmaf(au[u][i], au[u][i], qU);
    }
  }
  sH += __shfl_xor(sH, 16); qH += __shfl_xor(qH, 16);
  sU += __shfl_xor(sU, 16); qU += __shfl_xor(qU, 16);
  sH += __shfl_xor(sH, 32); qH += __shfl_xor(qH, 32);
  sU += __shfl_xor(sU, 32); qU += __shfl_xor(qU, 32);
  if (lane < 16) *(f32x4*)&redg[r * 4] = f32x4{sH, qH, sU, qU};
}

__device__ __forceinline__ void finish_step(
    const float* redb /* &red[g][0][0][0] */, int r,
    f32x4 (&az)[2], f32x4 (&ar)[2], f32x4 (&au)[2],
    const f32x4 (&xiz)[2], const f32x4 (&xir)[2], const f32x4 (&xwv)[2],
    f32x4 (&hold)[2], unsigned char* hbufg, const int (&hwadr)[2],
    float* orow, bool emit)
{
  f32x4 S = *(const f32x4*)&redb[r * 4];
  #pragma unroll
  for (int ww = 1; ww < 4; ++ww) S += *(const f32x4*)&redb[(ww * 16 + r) * 4];
  const float mH = S[0] * (1.f / 256.f);
  const float rsH = rsqrtf(fmaxf(S[1] * (1.f / 256.f) - mH * mH, 0.f) + 1e-5f);
  const float cH = -mH * rsH;
  const float mU = S[2] * (1.f / 128.f);
  const float rsU = rsqrtf(fmaxf(S[3] * (1.f / 128.f) - mU * mU, 0.f) + 1e-5f);
  const float cU = -mU * rsU;
  #pragma unroll
  for (int u = 0; u < 2; ++u) {
    f32x4 hn;
    #pragma unroll
    for (int i = 0; i < 4; ++i) {
      const float zg = fast_sig(xiz[u][i] + fmaf(az[u][i], rsH, cH));
      const float rg = fast_sig(xir[u][i] + fmaf(ar[u][i], rsH, cH));
      const float hu = fmaf(au[u][i], rsU, cU);
      const float hh = fast_tanh(fmaf(rg, hu, xwv[u][i]));
      hn[i] = fmaf(zg, hh - hold[u][i], hold[u][i]);
    }
    const unsigned lo  = (unsigned)bfb(hn[0]) | ((unsigned)bfb(hn[1]) << 16);
    const unsigned hi2 = (unsigned)bfb(hn[2]) | ((unsigned)bfb(hn[3]) << 16);
    *(uint2*)(hbufg + hwadr[u]) = uint2{lo, hi2};
    if (emit)
      *(float4*)(orow + 16 * u) = float4{hn[0], hn[1], hn[2], hn[3]};
    hold[u] = hn;
  }
}

__global__ __launch_bounds__(256, 1) void rec_kernel(
    const int* __restrict__ paths, const int* __restrict__ pmask,
    const int* __restrict__ perm,
    const float* __restrict__ bh, const float* __restrict__ bu,
    const float* __restrict__ xi_tab, const float* __restrict__ xw_tab,
    const s16x8* __restrict__ frags,
    float* __restrict__ out)
{
  __shared__ alignas(16) unsigned char hbuf[2][4096]; // per-group h, XOR(r)-swizzled
  __shared__ alignas(16) float red[2][4][16][4];      // per-group per-wave stats
  __shared__ int plT[2][32][16];                      // per-group paths [t][r]

  const int tid  = threadIdx.x;
  const int w    = tid >> 6;
  const int lane = tid & 63;
  const int s    = lane >> 4;
  const int r    = lane & 15;
  const int base = blockIdx.x * 32;
  const int gb0  = 32 * w + 4 * s;

  // persistent weight A-fragments (shared by both groups): 96 VGPR
  s16x8 wz[2][4], wr2[2][4], wu2[2][4];
  #pragma unroll
  for (int u = 0; u < 2; ++u) {
    const int T = 2 * w + u;
    #pragma unroll
    for (int kk = 0; kk < 4; ++kk) {
      wz[u][kk]  = frags[((0 * 8 + T) * 4 + kk) * 64 + lane];
      wr2[u][kk] = frags[((1 * 8 + T) * 4 + kk) * 64 + lane];
      wu2[u][kk] = frags[((2 * 8 + T) * 4 + kk) * 64 + lane];
    }
  }
  for (int k = tid; k < 1024; k += 256)    // plT[g][t][r]
    plT[k >> 9][(k >> 4) & 31][k & 15] = paths[perm[base + 16 * (k >> 9) + (k & 15)] * 32 + ((k >> 4) & 31)];
  ((uint4*)hbuf)[tid] = uint4{0u, 0u, 0u, 0u};
  ((uint4*)hbuf)[256 + tid] = uint4{0u, 0u, 0u, 0u};

  const int riA  = perm[base + r];
  const int riB  = perm[base + 16 + r];
  const int lenA = pmask[riA];
  const int lenB = pmask[riB];
  const int len_max = __shfl(lenB, 15);    // ascending bucket -> last row of B is block max

  f32x4 bz[2], br2[2], bu2[2];
  #pragma unroll
  for (int u = 0; u < 2; ++u) {
    bz[u]  = *(const f32x4*)(bh + gb0 + 16 * u);
    br2[u] = *(const f32x4*)(bh + 128 + gb0 + 16 * u);
    bu2[u] = *(const f32x4*)(bu + gb0 + 16 * u);
  }
  int hoff[4];
  #pragma unroll
  for (int kk = 0; kk < 4; ++kk)
    hoff[kk] = r * 256 + (((4 * kk + s) ^ r) << 4);
  int hwadr[2];
  #pragma unroll
  for (int u = 0; u < 2; ++u)
    hwadr[u] = r * 256 + (((4 * w + 2 * u + (s >> 1)) ^ r) << 4) + (s & 1) * 8;

  f32x4 holdA[2] = {f32x4{0.f,0.f,0.f,0.f}, f32x4{0.f,0.f,0.f,0.f}};
  f32x4 holdB[2] = {f32x4{0.f,0.f,0.f,0.f}, f32x4{0.f,0.f,0.f,0.f}};
  float* orowA = out + (size_t)riA * 256 + gb0;
  float* orowB = out + (size_t)riB * 256 + gb0;

  f32x4 azA[2], arA[2], auA[2], azB[2], arB[2], auB[2];
  f32x4 xizA[2], xirA[2], xwvA[2], xizB[2], xirB[2], xwvB[2];

  __syncthreads();   // staging done (also orders hbuf zeros vs prologue MFMA)

  { // tables t=0 for both groups
    const int pA = plT[0][0][r], pB = plT[1][0][r];
    #pragma unroll
    for (int u = 0; u < 2; ++u) {
      xizA[u] = *(const f32x4*)(xi_tab + pA * 256 + gb0 + 16 * u);
      xirA[u] = *(const f32x4*)(xi_tab + pA * 256 + 128 + gb0 + 16 * u);
      xwvA[u] = *(const f32x4*)(xw_tab + pA * 128 + gb0 + 16 * u);
      xizB[u] = *(const f32x4*)(xi_tab + pB * 256 + gb0 + 16 * u);
      xirB[u] = *(const f32x4*)(xi_tab + pB * 256 + 128 + gb0 + 16 * u);
      xwvB[u] = *(const f32x4*)(xw_tab + pB * 128 + gb0 + 16 * u);
    }
  }
  // prologue: start A(0)
  mfma_stats(hbuf[0], &red[0][w][0][0], hoff, wz, wr2, wu2, bz, br2, bu2, lane, r, azA, arA, auA);
  __syncthreads();

  #pragma unroll 1
  for (int t = 0; t < len_max; ++t) {
    const int tn = (t + 1 < len_max) ? t + 1 : t;
    // ---- phase 1: start B(t)  ∥  finish A(t) + prefetch A(t+1) ----
    mfma_stats(hbuf[1], &red[1][w][0][0], hoff, wz, wr2, wu2, bz, br2, bu2, lane, r, azB, arB, auB);
    {
      const int pA = plT[0][tn][r];
      f32x4 nxiz[2], nxir[2], nxwv[2];
      #pragma unroll
      for (int u = 0; u < 2; ++u) {
        nxiz[u] = *(const f32x4*)(xi_tab + pA * 256 + gb0 + 16 * u);
        nxir[u] = *(const f32x4*)(xi_tab + pA * 256 + 128 + gb0 + 16 * u);
        nxwv[u] = *(const f32x4*)(xw_tab + pA * 128 + gb0 + 16 * u);
      }
      finish_step(&red[0][0][0][0], r, azA, arA, auA, xizA, xirA, xwvA,
                  holdA, hbuf[0], hwadr, orowA, t == lenA - 1);
      #pragma unroll
      for (int u = 0; u < 2; ++u) { xizA[u] = nxiz[u]; xirA[u] = nxir[u]; xwvA[u] = nxwv[u]; }
    }
    __syncthreads();
    // ---- phase 2: start A(t+1)  ∥  finish B(t) + prefetch B(t+1) ----
    if (t + 1 < len_max)
      mfma_stats(hbuf[0], &red[0][w][0][0], hoff, wz, wr2, wu2, bz, br2, bu2, lane, r, azA, arA, auA);
    {
      const int pB = plT[1][tn][r];
      f32x4 nxiz[2], nxir[2], nxwv[2];
      #pragma unroll
      for (int u = 0; u < 2; ++u) {
        nxiz[u] = *(const f32x4*)(xi_tab + pB * 256 + gb0 + 16 * u);
        nxir[u] = *(const f32x4*)(xi_tab + pB * 256 + 128 + gb0 + 16 * u);
        nxwv[u] = *(const f32x4*)(xw_tab + pB * 128 + gb0 + 16 * u);
      }
      finish_step(&red[1][0][0][0], r, azB, arB, auB, xizB, xirB, xwvB,
                  holdB, hbuf[1], hwadr, orowB, t == lenB - 1);
      #pragma unroll
      for (int u = 0; u < 2; ++u) { xizB[u] = nxiz[u]; xirB[u] = nxir[u]; xwvB[u] = nxwv[u]; }
    }
    __syncthreads();
  }
}

// ---------- Phase 3: pair rows, final LN (verified) ----------
__global__ __launch_bounds__(256) void out_kernel(
    const float* __restrict__ gamma, const float* __restrict__ beta,
    float* __restrict__ out)
{
  const int tid = threadIdx.x;
  const int lane = tid & 63;
  const int m = blockIdx.x * 4 + (tid >> 6);
  float* pa = out + (size_t)(2 * m) * 256;
  float* pb = pa + 256;
  const float oa0 = pa[lane], oa1 = pa[64 + lane];
  const float ob0 = pb[lane], ob1 = pb[64 + lane];
  float s = oa0 + oa1 + ob0 + ob1;
  float q = oa0 * oa0 + oa1 * oa1 + ob0 * ob0 + ob1 * ob1;
  #pragma unroll
  for (int msk = 1; msk < 64; msk <<= 1) { s += __shfl_xor(s, msk); q += __shfl_xor(q, msk); }
  const float mean = s * (1.f / 256.f);
  const float rstd = rsqrtf(fmaxf(q * (1.f / 256.f) - mean * mean, 0.f) + 1e-5f);
  const float g0 = gamma[lane], g1 = gamma[64 + lane], g2 = gamma[128 + lane], g3 = gamma[192 + lane];
  const float b0 = beta[lane],  b1 = beta[64 + lane],  b2 = beta[128 + lane],  b3 = beta[192 + lane];
  const float na0 = (oa0 - mean) * rstd, na1 = (oa1 - mean) * rstd;
  const float nb0 = (ob0 - mean) * rstd, nb1 = (ob1 - mean) * rstd;
  pa[lane]       = na0 * g0 + b0;
  pa[64 + lane]  = na1 * g1 + b1;
  pa[128 + lane] = nb0 * g2 + b2;
  pa[192 + lane] = nb1 * g3 + b3;
  pb[lane]       = nb0 * g0 + b0;
  pb[64 + lane]  = nb1 * g1 + b1;
  pb[128 + lane] = na0 * g2 + b2;
  pb[192 + lane] = na1 * g3 + b3;
}

extern "C" void kernel_launch(void* const* d_in, const int* in_sizes, int n_in,
                              void* d_out, int out_size, void* d_ws, size_t ws_size,
                              hipStream_t stream) {
  const int*   paths = (const int*)d_in[0];
  const int*   pmask = (const int*)d_in[1];
  const float* emb   = (const float*)d_in[2];
  const float* Wi    = (const float*)d_in[3];
  const float* bi    = (const float*)d_in[4];
  const float* Wh    = (const float*)d_in[5];
  const float* bh    = (const float*)d_in[6];
  const float* Ww    = (const float*)d_in[7];
  const float* bw    = (const float*)d_in[8];
  const float* Wu    = (const float*)d_in[9];
  const float* bu    = (const float*)d_in[10];
  const float* gamma = (const float*)d_in[11];
  const float* beta  = (const float*)d_in[12];
  float* out = (float*)d_out;

  float* xi_tab = (float*)d_ws;                          // [301][256] f32
  float* xw_tab = xi_tab + 301 * 256;                    // [301][128] f32
  s16x8* frags  = (s16x8*)((char*)d_ws + 462336);        // [3*8*4][64] s16x8 = 96 KB
  int*   perm   = (int*)((char*)d_ws + 560640);          // [8192]

  hipLaunchKernelGGL(tab_kernel, dim3(310), dim3(256), 0, stream,
                     emb, Wi, bi, Ww, bw, Wh, Wu, pmask, perm, xi_tab, xw_tab, frags);
  hipLaunchKernelGGL(rec_kernel, dim3(256), dim3(256), 0, stream,
                     paths, pmask, perm, bh, bu, xi_tab, xw_tab, frags, out);
  hipLaunchKernelGGL(out_kernel, dim3(1024), dim3(256), 0, stream, gamma, beta, out);
}